// Round 5
// baseline (34480.185 us; speedup 1.0000x reference)
//
#include <hip/hip_runtime.h>
#include <math.h>

#define MD 1024
#define NWG_ADAM 16
#define RPB 64                                  // rows per Adam block
#define RPW 8                                   // rows per wave
#define BLK 512
#define TOTAL_BLOCKS 256
#define B_BLOCKS (TOTAL_BLOCKS - NWG_ADAM)      // 240 streaming blocks
#define WAVES_PER_BLOCK (BLK / 64)              // 8
#define B_WAVES (B_BLOCKS * WAVES_PER_BLOCK)    // 1920
#define BS_ROWS 65536
#define POLL_BAIL (1 << 17)   // deadlock insurance; legit detect is <1e3 iters

// workspace layout:
//   bytes  [0, 16384): u64 tagbuf[2][1024]  (gen<<32 | float bits) - memset/launch
//   floats [4096, 4112): 16 inter1 partials
//   floats [4112, 4352): 240 log-sigmoid partials
#define WS_I1_F 4096
#define WS_LS_F 4112

typedef unsigned long long u64t;

__device__ __forceinline__ void tag_store(u64t* p, unsigned gen, float v) {
  u64t x = ((u64t)gen << 32) | (u64t)__float_as_uint(v);
  __hip_atomic_store(p, x, __ATOMIC_RELAXED, __HIP_MEMORY_SCOPE_AGENT);
  // Compiler fence: a relaxed store may otherwise be sunk past the next
  // iteration's relaxed poll loads (legal reordering) -- if it sinks below
  // the spin loop, the loop waits on its own store => deadlock (R4 hang).
  asm volatile("" ::: "memory");
}

// select-combine: lane keeps `a` or `b` per sel, sums partner's other half.
__device__ __forceinline__ float comb2(float a, float b, int sel, int m) {
  float keep = sel ? b : a;
  float send = sel ? a : b;
  return keep + __shfl_xor(send, m);
}

// p[0..7] per-lane partials -> lane l holds full 64-lane sum of row (l&7).
__device__ __forceinline__ float reduce8(const float p[8], int lane) {
  float c01 = comb2(p[0], p[1], lane & 1, 1);
  float c23 = comb2(p[2], p[3], lane & 1, 1);
  float c45 = comb2(p[4], p[5], lane & 1, 1);
  float c67 = comb2(p[6], p[7], lane & 1, 1);
  float d03 = comb2(c01, c23, lane & 2, 2);
  float d47 = comb2(c45, c67, lane & 2, 2);
  float e   = comb2(d03, d47, lane & 4, 4);
  e += __shfl_xor(e, 8);
  e += __shfl_xor(e, 16);
  e += __shfl_xor(e, 32);
  return e;
}

__global__ __launch_bounds__(BLK, 2) void fused_kernel(
    const float* __restrict__ mean, const float* __restrict__ va,
    const float* __restrict__ xt, float* __restrict__ ws) {
  __shared__ float lds8[WAVES_PER_BLOCK];
  const int b = blockIdx.x;
  const int tid = (int)threadIdx.x;
  const int wv = tid >> 6;
  const int lane = tid & 63;

  if (b < NWG_ADAM) {
    // ---------------- Adam persistent blocks ----------------
    // Every wave owns 8 rows AND polls the full tag buffer itself.
    // Double-buffer safety: a wave stores gen t+1 only after seeing ALL
    // gen-t tags => every wave stored t => every wave finished reading
    // parity (t-1)&1 (its poll t-1 completed before its store of t, and
    // waves are 64-lane lockstep). Skew <= 1 step; every polling wave is
    // an awaited writer, so no starvation.
    u64t* tb = (u64t*)ws;                  // tagbuf[2][1024]
    const int rbase = b * RPB + wv * RPW;  // wave owns rows rbase..rbase+7
    // lane l holds Qsym[rbase+r][l + 64*j], r<8, j<16  (128 VGPRs)
    float q[8][16];
#pragma unroll
    for (int r = 0; r < 8; ++r)
#pragma unroll
      for (int j = 0; j < 16; ++j)
        q[r][j] = va[(size_t)(rbase + r) * MD + lane + 64 * j];
#pragma unroll
    for (int j = 0; j < 16; ++j) {
      const float* cp = va + (size_t)(lane + 64 * j) * MD + rbase;
      float4 c0 = *(const float4*)cp;
      float4 c1 = *(const float4*)(cp + 4);
      q[0][j] = 0.5f * (q[0][j] + c0.x);
      q[1][j] = 0.5f * (q[1][j] + c0.y);
      q[2][j] = 0.5f * (q[2][j] + c0.z);
      q[3][j] = 0.5f * (q[3][j] + c0.w);
      q[4][j] = 0.5f * (q[4][j] + c1.x);
      q[5][j] = 0.5f * (q[5][j] + c1.y);
      q[6][j] = 0.5f * (q[6][j] + c1.z);
      q[7][j] = 0.5f * (q[7][j] + c1.w);
    }

    const bool owner = (lane < RPW);
    const int myrow = rbase + lane;                 // valid when owner
    const float mmy = owner ? mean[myrow] : 0.f;
    float wcur = 1.f, mo = 0.f, vo = 0.f;

    if (owner) tag_store(tb + MD + myrow, 1u, 1.f - mmy);   // gen 1 -> buffer[1]

    float pb1 = 1.f, pb2 = 1.f;
    float a[16], p[8];

    for (unsigned t = 1; t <= 200; ++t) {
      // every wave polls the parity buffer for gen==t; on success the data
      // is already in registers.
      const u64t* src = tb + (size_t)(t & 1u) * MD;
      u64t v[16];
      bool ok;
      int spins = 0;
      asm volatile("" ::: "memory");
      do {
        ok = true;
#pragma unroll
        for (int j = 0; j < 16; ++j)
          v[j] = __hip_atomic_load(src + lane + 64 * j,
                                   __ATOMIC_RELAXED, __HIP_MEMORY_SCOPE_AGENT);
#pragma unroll
        for (int j = 0; j < 16; ++j) ok &= ((unsigned)(v[j] >> 32) == t);
        if (++spins > POLL_BAIL) break;   // deadlock insurance (never in healthy runs)
      } while (__any(!ok));
#pragma unroll
      for (int j = 0; j < 16; ++j) a[j] = __uint_as_float((unsigned)v[j]);

#pragma unroll
      for (int r = 0; r < 8; ++r) {
        float s = 0.f;
#pragma unroll
        for (int j = 0; j < 16; ++j) s = fmaf(q[r][j], a[j], s);
        p[r] = s;
      }
      float e = reduce8(p, lane);   // lane l: g for row rbase+(l&7)

      if (t == 200) {
        // final: e = (Qsym aa)_row ; inter1 partial = sum aa_row * e
        float contrib = owner ? (wcur - mmy) * e : 0.f;
#pragma unroll
        for (int m = 1; m < 64; m <<= 1) contrib += __shfl_xor(contrib, m);
        if (lane == 0) lds8[wv] = contrib;
        __syncthreads();
        if (tid == 0) {
          float s = 0.f;
#pragma unroll
          for (int i = 0; i < WAVES_PER_BLOCK; ++i) s += lds8[i];
          ws[WS_I1_F + b] = s;
        }
        break;
      }

      pb1 *= 0.9f; pb2 *= 0.999f;
      if (owner) {
        mo = 0.9f * mo + 0.1f * e;
        vo = 0.999f * vo + 0.001f * (e * e);
        float mhat = mo / (1.f - pb1);
        float vhat = vo / (1.f - pb2);
        wcur -= 0.1f * mhat / (sqrtf(vhat) + 1e-8f);
        tag_store(tb + (size_t)((t + 1) & 1u) * MD + myrow, t + 1, wcur - mmy);
      }
    }
  } else {
    // ---------------- log-sigmoid streaming blocks ----------------
    const int gw = (b - NWG_ADAM) * WAVES_PER_BLOCK + wv;
    const float4* mp = (const float4*)mean;
    float4 m0 = mp[0 * 64 + lane];
    float4 m1 = mp[1 * 64 + lane];
    float4 m2 = mp[2 * 64 + lane];
    float4 m3 = mp[3 * 64 + lane];
    float lsum = 0.f;
    for (int row = gw; row < BS_ROWS; row += B_WAVES) {
      const float4* xr = (const float4*)(xt + (size_t)row * MD);
      float4 x0 = xr[0 * 64 + lane];
      float4 x1 = xr[1 * 64 + lane];
      float4 x2 = xr[2 * 64 + lane];
      float4 x3 = xr[3 * 64 + lane];
      float acc = 0.f;
      acc = fmaf(x0.x, m0.x, acc); acc = fmaf(x0.y, m0.y, acc);
      acc = fmaf(x0.z, m0.z, acc); acc = fmaf(x0.w, m0.w, acc);
      acc = fmaf(x1.x, m1.x, acc); acc = fmaf(x1.y, m1.y, acc);
      acc = fmaf(x1.z, m1.z, acc); acc = fmaf(x1.w, m1.w, acc);
      acc = fmaf(x2.x, m2.x, acc); acc = fmaf(x2.y, m2.y, acc);
      acc = fmaf(x2.z, m2.z, acc); acc = fmaf(x2.w, m2.w, acc);
      acc = fmaf(x3.x, m3.x, acc); acc = fmaf(x3.y, m3.y, acc);
      acc = fmaf(x3.z, m3.z, acc); acc = fmaf(x3.w, m3.w, acc);
#pragma unroll
      for (int m = 1; m < 64; m <<= 1) acc += __shfl_xor(acc, m);
      if (lane == 0) {
        float z = fminf(acc, 0.f);
        lsum += z - log1pf(expf(-fabsf(acc)));
      }
    }
    if (lane == 0) lds8[wv] = lsum;
    __syncthreads();
    if (tid == 0) {
      float s = 0.f;
#pragma unroll
      for (int i = 0; i < WAVES_PER_BLOCK; ++i) s += lds8[i];
      ws[WS_LS_F + (b - NWG_ADAM)] = s;
    }
  }
}

__global__ void finalize_kernel(const float* __restrict__ ws, float* __restrict__ out) {
  const int lane = (int)threadIdx.x & 63;
  float qsum = (lane < NWG_ADAM) ? ws[WS_I1_F + lane] : 0.f;
  float lssum = 0.f;
  for (int i = lane; i < B_BLOCKS; i += 64) lssum += ws[WS_LS_F + i];
#pragma unroll
  for (int m = 1; m < 64; m <<= 1) {
    qsum += __shfl_xor(qsum, m);
    lssum += __shfl_xor(lssum, m);
  }
  if (lane == 0) out[0] = 0.5f * qsum - lssum;
}

extern "C" void kernel_launch(void* const* d_in, const int* in_sizes, int n_in,
                              void* d_out, int out_size, void* d_ws, size_t ws_size,
                              hipStream_t stream) {
  (void)in_sizes; (void)n_in; (void)out_size; (void)ws_size;
  const float* mean = (const float*)d_in[0];
  const float* va   = (const float*)d_in[1];
  const float* xt   = (const float*)d_in[2];
  float* out = (float*)d_out;
  float* ws  = (float*)d_ws;

  // reset the tagged-aa double buffer (gens must start at 0 every launch)
  hipMemsetAsync(d_ws, 0, 2 * MD * sizeof(u64t), stream);
  fused_kernel<<<TOTAL_BLOCKS, BLK, 0, stream>>>(mean, va, xt, ws);
  finalize_kernel<<<1, 64, 0, stream>>>(ws, out);
}

// Round 7
// 594.553 us; speedup vs baseline: 57.9935x; 57.9935x over previous
//
#include <hip/hip_runtime.h>
#include <math.h>

#define MD 1024
#define NWG_ADAM 16
#define RPB 64                                  // rows per Adam block
#define RPW 8                                   // rows per wave
#define BLK 512
#define TOTAL_BLOCKS 256
#define B_BLOCKS (TOTAL_BLOCKS - NWG_ADAM)      // 240 streaming blocks
#define WAVES_PER_BLOCK (BLK / 64)              // 8
#define B_WAVES (B_BLOCKS * WAVES_PER_BLOCK)    // 1920
#define BS_ROWS 65536
#define POLL_BAIL (1 << 17)   // deadlock insurance; legit detect is <1e3 iters

// workspace layout:
//   bytes  [0, 16384): u64 tagbuf[2][1024]  (gen<<32 | float bits) - memset/launch
//   floats [4096, 4112): 16 inter1 partials
//   floats [4112, 4352): 240 log-sigmoid partials
#define WS_I1_F 4096
#define WS_LS_F 4112

typedef unsigned long long u64t;
typedef float f32x4 __attribute__((ext_vector_type(4)));

__device__ __forceinline__ void tag_store(u64t* p, unsigned gen, float v) {
  u64t x = ((u64t)gen << 32) | (u64t)__float_as_uint(v);
  __hip_atomic_store(p, x, __ATOMIC_RELAXED, __HIP_MEMORY_SCOPE_AGENT);
  // Compiler fence: forbid sinking this relaxed store below a later relaxed
  // poll loop (the R4 deadlock).
  asm volatile("" ::: "memory");
}

__device__ __forceinline__ float4 ldnt(const float4* p) {
  f32x4 r = __builtin_nontemporal_load((const f32x4*)p);
  return make_float4(r.x, r.y, r.z, r.w);
}

// select-combine: lane keeps `a` or `b` per sel, sums partner's other half.
__device__ __forceinline__ float comb2(float a, float b, int sel, int m) {
  float keep = sel ? b : a;
  float send = sel ? a : b;
  return keep + __shfl_xor(send, m);
}

// p[0..7] per-lane partials -> lane l holds full 64-lane sum of row (l&7).
__device__ __forceinline__ float reduce8(const float p[8], int lane) {
  float c01 = comb2(p[0], p[1], lane & 1, 1);
  float c23 = comb2(p[2], p[3], lane & 1, 1);
  float c45 = comb2(p[4], p[5], lane & 1, 1);
  float c67 = comb2(p[6], p[7], lane & 1, 1);
  float d03 = comb2(c01, c23, lane & 2, 2);
  float d47 = comb2(c45, c67, lane & 2, 2);
  float e   = comb2(d03, d47, lane & 4, 4);
  e += __shfl_xor(e, 8);
  e += __shfl_xor(e, 16);
  e += __shfl_xor(e, 32);
  return e;
}

__global__ __launch_bounds__(BLK, 2) void fused_kernel(
    const float* __restrict__ mean, const float* __restrict__ va,
    const float* __restrict__ xt, float* __restrict__ ws) {
  __shared__ float aas[MD];
  __shared__ float lds8[WAVES_PER_BLOCK];
  const int b = blockIdx.x;
  const int tid = (int)threadIdx.x;
  const int wv = tid >> 6;
  const int lane = tid & 63;

  if (b < NWG_ADAM) {
    // ---------------- Adam persistent blocks ----------------
    // wave0 is the block's only poller (R5 lesson: poll traffic is a global
    // fabric resource -- minimize pollers). Poll segment j == publisher
    // block j's 64 rows; laggard bitmask re-polls only missing segments and
    // stages each to LDS as it arrives.
    u64t* tb = (u64t*)ws;                  // tagbuf[2][1024]
    const int rbase = b * RPB + wv * RPW;  // wave owns rows rbase..rbase+7
    // lane l holds Qsym[rbase+r][l + 64*j], r<8, j<16  (128 VGPRs)
    float q[8][16];
#pragma unroll
    for (int r = 0; r < 8; ++r)
#pragma unroll
      for (int j = 0; j < 16; ++j)
        q[r][j] = va[(size_t)(rbase + r) * MD + lane + 64 * j];
#pragma unroll
    for (int j = 0; j < 16; ++j) {
      const float* cp = va + (size_t)(lane + 64 * j) * MD + rbase;
      float4 c0 = *(const float4*)cp;
      float4 c1 = *(const float4*)(cp + 4);
      q[0][j] = 0.5f * (q[0][j] + c0.x);
      q[1][j] = 0.5f * (q[1][j] + c0.y);
      q[2][j] = 0.5f * (q[2][j] + c0.z);
      q[3][j] = 0.5f * (q[3][j] + c0.w);
      q[4][j] = 0.5f * (q[4][j] + c1.x);
      q[5][j] = 0.5f * (q[5][j] + c1.y);
      q[6][j] = 0.5f * (q[6][j] + c1.z);
      q[7][j] = 0.5f * (q[7][j] + c1.w);
    }

    const bool owner = (lane < RPW);
    const int myrow = rbase + lane;                 // valid when owner
    const float mmy = owner ? mean[myrow] : 0.f;
    float wcur = 1.f, mo = 0.f, vo = 0.f;

    if (owner) tag_store(tb + MD + myrow, 1u, 1.f - mmy);   // gen 1 -> buffer[1]

    float pb1 = 1.f, pb2 = 1.f;
    float a[16], p[8];

    for (unsigned t = 1; t <= 200; ++t) {
      // bias-correction reciprocals: independent of g, overlap with the poll
      pb1 *= 0.9f; pb2 *= 0.999f;
      const float inv1 = 1.f / (1.f - pb1);
      const float inv2 = 1.f / (1.f - pb2);

      if (wv == 0) {
        const u64t* src = tb + (size_t)(t & 1u) * MD;
        unsigned pend = 0xFFFFu;
        int spins = 0;
        u64t v[16];
        asm volatile("" ::: "memory");
        while (pend) {
#pragma unroll
          for (int j = 0; j < 16; ++j)
            if (pend & (1u << j))
              v[j] = __hip_atomic_load(src + lane + 64 * j,
                                       __ATOMIC_RELAXED, __HIP_MEMORY_SCOPE_AGENT);
#pragma unroll
          for (int j = 0; j < 16; ++j)
            if (pend & (1u << j)) {
              const bool okj = ((unsigned)(v[j] >> 32) == t);
              if (__all(okj)) {
                aas[lane + 64 * j] = __uint_as_float((unsigned)v[j]);
                pend &= ~(1u << j);
              }
            }
          if (++spins > POLL_BAIL) break;   // insurance, never in healthy runs
        }
      }
      __syncthreads();
#pragma unroll
      for (int j = 0; j < 16; ++j) a[j] = aas[lane + 64 * j];

#pragma unroll
      for (int r = 0; r < 8; ++r) {
        float s = 0.f;
#pragma unroll
        for (int j = 0; j < 16; ++j) s = fmaf(q[r][j], a[j], s);
        p[r] = s;
      }
      float e = reduce8(p, lane);   // lane l: g for row rbase+(l&7)

      if (t == 200) {
        // final: e = (Qsym aa)_row ; inter1 partial = sum aa_row * e
        float contrib = owner ? (wcur - mmy) * e : 0.f;
#pragma unroll
        for (int m = 1; m < 64; m <<= 1) contrib += __shfl_xor(contrib, m);
        if (lane == 0) lds8[wv] = contrib;
        __syncthreads();
        if (tid == 0) {
          float s = 0.f;
#pragma unroll
          for (int i = 0; i < WAVES_PER_BLOCK; ++i) s += lds8[i];
          ws[WS_I1_F + b] = s;
        }
        break;
      }

      if (owner) {
        mo = 0.9f * mo + 0.1f * e;
        vo = 0.999f * vo + 0.001f * (e * e);
        float mhat = mo * inv1;
        float vhat = vo * inv2;
        wcur -= 0.1f * mhat / (sqrtf(vhat) + 1e-8f);
        tag_store(tb + (size_t)((t + 1) & 1u) * MD + myrow, t + 1, wcur - mmy);
      }
      // no barrier here: next iteration's poll/syncthreads re-synchronizes
    }
  } else {
    // ---------------- log-sigmoid streaming blocks ----------------
    // xt is zero-reuse: non-temporal loads keep it out of the LLC that the
    // Adam tag exchange lives in (mutual interference, R3 counters).
    const int gw = (b - NWG_ADAM) * WAVES_PER_BLOCK + wv;
    const float4* mp = (const float4*)mean;
    float4 m0 = mp[0 * 64 + lane];
    float4 m1 = mp[1 * 64 + lane];
    float4 m2 = mp[2 * 64 + lane];
    float4 m3 = mp[3 * 64 + lane];
    float lsum = 0.f;
    for (int row = gw; row < BS_ROWS; row += B_WAVES) {
      const float4* xr = (const float4*)(xt + (size_t)row * MD);
      float4 x0 = ldnt(xr + 0 * 64 + lane);
      float4 x1 = ldnt(xr + 1 * 64 + lane);
      float4 x2 = ldnt(xr + 2 * 64 + lane);
      float4 x3 = ldnt(xr + 3 * 64 + lane);
      float acc = 0.f;
      acc = fmaf(x0.x, m0.x, acc); acc = fmaf(x0.y, m0.y, acc);
      acc = fmaf(x0.z, m0.z, acc); acc = fmaf(x0.w, m0.w, acc);
      acc = fmaf(x1.x, m1.x, acc); acc = fmaf(x1.y, m1.y, acc);
      acc = fmaf(x1.z, m1.z, acc); acc = fmaf(x1.w, m1.w, acc);
      acc = fmaf(x2.x, m2.x, acc); acc = fmaf(x2.y, m2.y, acc);
      acc = fmaf(x2.z, m2.z, acc); acc = fmaf(x2.w, m2.w, acc);
      acc = fmaf(x3.x, m3.x, acc); acc = fmaf(x3.y, m3.y, acc);
      acc = fmaf(x3.z, m3.z, acc); acc = fmaf(x3.w, m3.w, acc);
#pragma unroll
      for (int m = 1; m < 64; m <<= 1) acc += __shfl_xor(acc, m);
      if (lane == 0) {
        float z = fminf(acc, 0.f);
        lsum += z - log1pf(expf(-fabsf(acc)));
      }
    }
    if (lane == 0) lds8[wv] = lsum;
    __syncthreads();
    if (tid == 0) {
      float s = 0.f;
#pragma unroll
      for (int i = 0; i < WAVES_PER_BLOCK; ++i) s += lds8[i];
      ws[WS_LS_F + (b - NWG_ADAM)] = s;
    }
  }
}

__global__ void finalize_kernel(const float* __restrict__ ws, float* __restrict__ out) {
  const int lane = (int)threadIdx.x & 63;
  float qsum = (lane < NWG_ADAM) ? ws[WS_I1_F + lane] : 0.f;
  float lssum = 0.f;
  for (int i = lane; i < B_BLOCKS; i += 64) lssum += ws[WS_LS_F + i];
#pragma unroll
  for (int m = 1; m < 64; m <<= 1) {
    qsum += __shfl_xor(qsum, m);
    lssum += __shfl_xor(lssum, m);
  }
  if (lane == 0) out[0] = 0.5f * qsum - lssum;
}

extern "C" void kernel_launch(void* const* d_in, const int* in_sizes, int n_in,
                              void* d_out, int out_size, void* d_ws, size_t ws_size,
                              hipStream_t stream) {
  (void)in_sizes; (void)n_in; (void)out_size; (void)ws_size;
  const float* mean = (const float*)d_in[0];
  const float* va   = (const float*)d_in[1];
  const float* xt   = (const float*)d_in[2];
  float* out = (float*)d_out;
  float* ws  = (float*)d_ws;

  // reset the tagged-aa double buffer (gens must start at 0 every launch)
  (void)hipMemsetAsync(d_ws, 0, 2 * MD * sizeof(u64t), stream);
  fused_kernel<<<TOTAL_BLOCKS, BLK, 0, stream>>>(mean, va, xt, ws);
  finalize_kernel<<<1, 64, 0, stream>>>(ws, out);
}

// Round 8
// 448.816 us; speedup vs baseline: 76.8248x; 1.3247x over previous
//
#include <hip/hip_runtime.h>
#include <math.h>

#define MD 1024
#define NWG_ADAM 16
#define RPB 64                                  // rows per Adam block
#define RPW 8                                   // rows per wave (publish)
#define PW 128                                  // rows polled per wave (2 segments)
#define BLK 512
#define TOTAL_BLOCKS 256
#define B_BLOCKS (TOTAL_BLOCKS - NWG_ADAM)      // 240 streaming blocks
#define WAVES_PER_BLOCK (BLK / 64)              // 8
#define B_WAVES (B_BLOCKS * WAVES_PER_BLOCK)    // 1920
#define BS_ROWS 65536
#define POLL_BAIL (1 << 17)   // deadlock insurance; legit detect is <1e3 iters

// workspace layout:
//   bytes  [0, 16384): u64 tagbuf[2][1024]  (gen<<32 | float bits) - memset/launch
//   floats [4096, 4112): 16 inter1 partials
//   floats [4112, 4352): 240 log-sigmoid partials
#define WS_I1_F 4096
#define WS_LS_F 4112

typedef unsigned long long u64t;
typedef unsigned int u32x4 __attribute__((ext_vector_type(4)));

__device__ __forceinline__ void tag_store(u64t* p, unsigned gen, float v) {
  u64t x = ((u64t)gen << 32) | (u64t)__float_as_uint(v);
  __hip_atomic_store(p, x, __ATOMIC_RELAXED, __HIP_MEMORY_SCOPE_AGENT);
  // Compiler fence: forbid sinking this relaxed store below a later relaxed
  // poll loop (the R4 deadlock).
  asm volatile("" ::: "memory");
}

// 16B coherent poll load: two adjacent (gen,val) u64s in one dwordx4.
// sc0 sc1 bypasses L1 and the (non-cross-coherent) XCD L2 so remote
// publishers' LLC stores are visible; each 8B half is transaction-atomic.
__device__ __forceinline__ u32x4 poll16(const u64t* p) {
  u32x4 r;
  asm volatile("global_load_dwordx4 %0, %1, off sc0 sc1\n\t"
               "s_waitcnt vmcnt(0)"
               : "=v"(r) : "v"(p) : "memory");
  return r;
}

// select-combine: lane keeps `a` or `b` per sel, sums partner's other half.
__device__ __forceinline__ float comb2(float a, float b, int sel, int m) {
  float keep = sel ? b : a;
  float send = sel ? a : b;
  return keep + __shfl_xor(send, m);
}

// p[0..7] per-lane partials -> lane l holds full 64-lane sum of row (l&7).
__device__ __forceinline__ float reduce8(const float p[8], int lane) {
  float c01 = comb2(p[0], p[1], lane & 1, 1);
  float c23 = comb2(p[2], p[3], lane & 1, 1);
  float c45 = comb2(p[4], p[5], lane & 1, 1);
  float c67 = comb2(p[6], p[7], lane & 1, 1);
  float d03 = comb2(c01, c23, lane & 2, 2);
  float d47 = comb2(c45, c67, lane & 2, 2);
  float e   = comb2(d03, d47, lane & 4, 4);
  e += __shfl_xor(e, 8);
  e += __shfl_xor(e, 16);
  e += __shfl_xor(e, 32);
  return e;
}

__global__ __launch_bounds__(BLK, 2) void fused_kernel(
    const float* __restrict__ mean, const float* __restrict__ va,
    const float* __restrict__ xt, float* __restrict__ ws) {
  __shared__ float aas[MD];
  __shared__ float lds8[WAVES_PER_BLOCK];
  const int b = blockIdx.x;
  const int tid = (int)threadIdx.x;
  const int wv = tid >> 6;
  const int lane = tid & 63;

  if (b < NWG_ADAM) {
    // ---------------- Adam persistent blocks ----------------
    // Disjoint-subset polling: wave w polls ONLY rows [128w,128w+128)
    // (publisher blocks 2w,2w+1) with one dwordx4 per round, staging to
    // LDS in parallel. Total fabric traffic per round == R3's wave0-only
    // scheme (2048 lines); rounds are ~16x shorter.
    u64t* tb = (u64t*)ws;                  // tagbuf[2][1024]
    const int rbase = b * RPB + wv * RPW;  // wave publishes rows rbase..rbase+7
    // lane l holds Qsym[rbase+r][l + 64*j], r<8, j<16  (128 VGPRs)
    float q[8][16];
#pragma unroll
    for (int r = 0; r < 8; ++r)
#pragma unroll
      for (int j = 0; j < 16; ++j)
        q[r][j] = va[(size_t)(rbase + r) * MD + lane + 64 * j];
#pragma unroll
    for (int j = 0; j < 16; ++j) {
      const float* cp = va + (size_t)(lane + 64 * j) * MD + rbase;
      float4 c0 = *(const float4*)cp;
      float4 c1 = *(const float4*)(cp + 4);
      q[0][j] = 0.5f * (q[0][j] + c0.x);
      q[1][j] = 0.5f * (q[1][j] + c0.y);
      q[2][j] = 0.5f * (q[2][j] + c0.z);
      q[3][j] = 0.5f * (q[3][j] + c0.w);
      q[4][j] = 0.5f * (q[4][j] + c1.x);
      q[5][j] = 0.5f * (q[5][j] + c1.y);
      q[6][j] = 0.5f * (q[6][j] + c1.z);
      q[7][j] = 0.5f * (q[7][j] + c1.w);
    }

    const bool owner = (lane < RPW);
    const int myrow = rbase + lane;                 // valid when owner
    const float mmy = owner ? mean[myrow] : 0.f;
    float wcur = 1.f, mo = 0.f, vo = 0.f;

    if (owner) tag_store(tb + MD + myrow, 1u, 1.f - mmy);   // gen 1 -> buffer[1]

    float pb1 = 1.f, pb2 = 1.f;
    float a[16], p[8];

    for (unsigned t = 1; t <= 200; ++t) {
      // bias-correction reciprocals: independent of g, overlap with the poll
      pb1 *= 0.9f; pb2 *= 0.999f;
      const float inv1 = 1.f / (1.f - pb1);
      const float inv2 = 1.f / (1.f - pb2);

      {
        const u64t* src = tb + (size_t)(t & 1u) * MD + PW * wv + 2 * lane;
        u32x4 r;
        bool ok;
        int spins = 0;
        do {
          r = poll16(src);                       // rows 128w+2l, 128w+2l+1
          ok = (r.y == t) & (r.w == t);          // gen tags in hi dwords
          if (++spins > POLL_BAIL) break;        // insurance, never healthy
        } while (__any(!ok));
        *(float2*)(aas + PW * wv + 2 * lane) =
            make_float2(__uint_as_float(r.x), __uint_as_float(r.z));
      }
      __syncthreads();
#pragma unroll
      for (int j = 0; j < 16; ++j) a[j] = aas[lane + 64 * j];

#pragma unroll
      for (int r = 0; r < 8; ++r) {
        float s = 0.f;
#pragma unroll
        for (int j = 0; j < 16; ++j) s = fmaf(q[r][j], a[j], s);
        p[r] = s;
      }
      float e = reduce8(p, lane);   // lane l: g for row rbase+(l&7)

      if (t == 200) {
        // final: e = (Qsym aa)_row ; inter1 partial = sum aa_row * e
        float contrib = owner ? (wcur - mmy) * e : 0.f;
#pragma unroll
        for (int m = 1; m < 64; m <<= 1) contrib += __shfl_xor(contrib, m);
        if (lane == 0) lds8[wv] = contrib;
        __syncthreads();
        if (tid == 0) {
          float s = 0.f;
#pragma unroll
          for (int i = 0; i < WAVES_PER_BLOCK; ++i) s += lds8[i];
          ws[WS_I1_F + b] = s;
        }
        break;
      }

      if (owner) {
        mo = 0.9f * mo + 0.1f * e;
        vo = 0.999f * vo + 0.001f * (e * e);
        float mhat = mo * inv1;
        float vhat = vo * inv2;
        wcur -= 0.1f * mhat / (sqrtf(vhat) + 1e-8f);
        tag_store(tb + (size_t)((t + 1) & 1u) * MD + myrow, t + 1, wcur - mmy);
      }
      // no barrier here: next iteration's poll + syncthreads re-synchronizes
    }
  } else {
    // ---------------- log-sigmoid streaming blocks ----------------
    const int gw = (b - NWG_ADAM) * WAVES_PER_BLOCK + wv;
    const float4* mp = (const float4*)mean;
    float4 m0 = mp[0 * 64 + lane];
    float4 m1 = mp[1 * 64 + lane];
    float4 m2 = mp[2 * 64 + lane];
    float4 m3 = mp[3 * 64 + lane];
    float lsum = 0.f;
    for (int row = gw; row < BS_ROWS; row += B_WAVES) {
      const float4* xr = (const float4*)(xt + (size_t)row * MD);
      float4 x0 = xr[0 * 64 + lane];
      float4 x1 = xr[1 * 64 + lane];
      float4 x2 = xr[2 * 64 + lane];
      float4 x3 = xr[3 * 64 + lane];
      float acc = 0.f;
      acc = fmaf(x0.x, m0.x, acc); acc = fmaf(x0.y, m0.y, acc);
      acc = fmaf(x0.z, m0.z, acc); acc = fmaf(x0.w, m0.w, acc);
      acc = fmaf(x1.x, m1.x, acc); acc = fmaf(x1.y, m1.y, acc);
      acc = fmaf(x1.z, m1.z, acc); acc = fmaf(x1.w, m1.w, acc);
      acc = fmaf(x2.x, m2.x, acc); acc = fmaf(x2.y, m2.y, acc);
      acc = fmaf(x2.z, m2.z, acc); acc = fmaf(x2.w, m2.w, acc);
      acc = fmaf(x3.x, m3.x, acc); acc = fmaf(x3.y, m3.y, acc);
      acc = fmaf(x3.z, m3.z, acc); acc = fmaf(x3.w, m3.w, acc);
#pragma unroll
      for (int m = 1; m < 64; m <<= 1) acc += __shfl_xor(acc, m);
      if (lane == 0) {
        float z = fminf(acc, 0.f);
        lsum += z - log1pf(expf(-fabsf(acc)));
      }
    }
    if (lane == 0) lds8[wv] = lsum;
    __syncthreads();
    if (tid == 0) {
      float s = 0.f;
#pragma unroll
      for (int i = 0; i < WAVES_PER_BLOCK; ++i) s += lds8[i];
      ws[WS_LS_F + (b - NWG_ADAM)] = s;
    }
  }
}

__global__ void finalize_kernel(const float* __restrict__ ws, float* __restrict__ out) {
  const int lane = (int)threadIdx.x & 63;
  float qsum = (lane < NWG_ADAM) ? ws[WS_I1_F + lane] : 0.f;
  float lssum = 0.f;
  for (int i = lane; i < B_BLOCKS; i += 64) lssum += ws[WS_LS_F + i];
#pragma unroll
  for (int m = 1; m < 64; m <<= 1) {
    qsum += __shfl_xor(qsum, m);
    lssum += __shfl_xor(lssum, m);
  }
  if (lane == 0) out[0] = 0.5f * qsum - lssum;
}

extern "C" void kernel_launch(void* const* d_in, const int* in_sizes, int n_in,
                              void* d_out, int out_size, void* d_ws, size_t ws_size,
                              hipStream_t stream) {
  (void)in_sizes; (void)n_in; (void)out_size; (void)ws_size;
  const float* mean = (const float*)d_in[0];
  const float* va   = (const float*)d_in[1];
  const float* xt   = (const float*)d_in[2];
  float* out = (float*)d_out;
  float* ws  = (float*)d_ws;

  // reset the tagged-aa double buffer (gens must start at 0 every launch)
  (void)hipMemsetAsync(d_ws, 0, 2 * MD * sizeof(u64t), stream);
  fused_kernel<<<TOTAL_BLOCKS, BLK, 0, stream>>>(mean, va, xt, ws);
  finalize_kernel<<<1, 64, 0, stream>>>(ws, out);
}